// Round 5
// baseline (17705.368 us; speedup 1.0000x reference)
//
#include <hip/hip_runtime.h>
#include <math.h>

#define N_PTS 16384
#define KNN_K 32
#define KEEP 48            // per-slice candidate list; union re-scored np-style
#define NSLICE 4
#define CAND_TOT (KEEP * NSLICE)   // 192 candidates per query into the refine
#define HDIM 128

// ---------------------------------------------------------------------------
// numpy-pairwise fp32 sum of squares per row: replicates np.sum(x*x, axis=1)
// (8 accumulators over the contiguous axis, tree-combined), rounding locked.
template<int C>
__global__ void sqnorm_np_kernel(const float* __restrict__ feat, float* __restrict__ sq) {
  int r = blockIdx.x * 256 + threadIdx.x;
  if (r >= N_PTS) return;
  const float* xr = feat + (size_t)r * C;
  float acc[8];
  #pragma unroll
  for (int j = 0; j < 8; j++) acc[j] = __fmul_rn(xr[j], xr[j]);
  for (int i = 8; i < C; i += 8) {
    #pragma unroll
    for (int j = 0; j < 8; j++)
      acc[j] = __fadd_rn(acc[j], __fmul_rn(xr[i + j], xr[i + j]));
  }
  float s01 = __fadd_rn(acc[0], acc[1]);
  float s23 = __fadd_rn(acc[2], acc[3]);
  float s45 = __fadd_rn(acc[4], acc[5]);
  float s67 = __fadd_rn(acc[6], acc[7]);
  sq[r] = __fadd_rn(__fadd_rn(s01, s23), __fadd_rn(s45, s67));
}

// ---------------------------------------------------------------------------
// KNN candidate pass (fp32), candidate-dim sliced 4x for occupancy:
// block (qtile, slice) = 64 queries vs 4096 candidates in 64-wide tiles.
// Register-tiled 64x64 distance GEMM (4x4/thread); wave-0 threads (one per
// query) keep the slice's KEEP smallest in registers. Union over slices
// contains the global top-48 (in-slice rank <= global rank).
template<int C>
__launch_bounds__(256)
__global__ void knn_cand_kernel(const float* __restrict__ feat, const float* __restrict__ sq,
                                int* __restrict__ cand_out) {
  constexpr int QI = 64, NJ = 64;
  constexpr int SLICE = N_PTS / NSLICE;      // 4096
  constexpr int KCH = (C == 64) ? 64 : 32;
  constexpr int SPA = C + 4;
  constexpr int SPB = KCH + 4;
  __shared__ float Aq[QI * SPA];
  __shared__ float Bt[NJ * SPB];
  __shared__ float Dist[QI * 65];
  __shared__ float sqq[QI];

  const int t = threadIdx.x;
  const int qbase = blockIdx.x * QI;
  const int slice = blockIdx.y;
  const int jbase = slice * SLICE;
  const int tx = t & 15, ty = t >> 4;

  for (int v = t; v < QI * C / 4; v += 256) {
    int r = v / (C / 4), c4 = v % (C / 4);
    float4 f = *(const float4*)(feat + (size_t)(qbase + r) * C + c4 * 4);
    *(float4*)(&Aq[r * SPA + c4 * 4]) = f;
  }
  if (t < QI) sqq[t] = sq[qbase + t];

  float ld[KEEP]; int li[KEEP];
  #pragma unroll
  for (int s = 0; s < KEEP; s++) { ld[s] = INFINITY; li[s] = 0; }
  float maxv = INFINITY; int maxp = 0;

  for (int j0 = jbase; j0 < jbase + SLICE; j0 += NJ) {
    float acc[4][4] = {};
    for (int kc = 0; kc < C; kc += KCH) {
      __syncthreads();   // also orders prev selection before Bt/Dist reuse
      for (int v = t; v < NJ * KCH / 4; v += 256) {
        int r = v / (KCH / 4), c4 = v % (KCH / 4);
        float4 f = *(const float4*)(feat + (size_t)(j0 + r) * C + kc + c4 * 4);
        *(float4*)(&Bt[r * SPB + c4 * 4]) = f;
      }
      __syncthreads();
      #pragma unroll
      for (int kk = 0; kk < KCH; kk += 4) {
        float4 a[4], b[4];
        #pragma unroll
        for (int i = 0; i < 4; i++) a[i] = *(const float4*)(&Aq[(ty + 16*i)*SPA + kc + kk]);
        #pragma unroll
        for (int i = 0; i < 4; i++) b[i] = *(const float4*)(&Bt[(tx + 16*i)*SPB + kk]);
        #pragma unroll
        for (int i = 0; i < 4; i++)
          #pragma unroll
          for (int j = 0; j < 4; j++)
            acc[i][j] += a[i].x*b[j].x + a[i].y*b[j].y + a[i].z*b[j].z + a[i].w*b[j].w;
      }
    }
    #pragma unroll
    for (int i = 0; i < 4; i++) {
      float si = sqq[ty + 16*i];
      #pragma unroll
      for (int j = 0; j < 4; j++) {
        int c = tx + 16*j;
        Dist[(ty + 16*i)*65 + c] = si + sq[j0 + c] - 2.f*acc[i][j];
      }
    }
    __syncthreads();
    if (t < QI) {
      const int gi = qbase + t;
      for (int c = 0; c < NJ; c++) {
        float d = Dist[t*65 + c];
        int j = j0 + c;
        if (d < maxv && j != gi) {
          #pragma unroll
          for (int s = 0; s < KEEP; s++) if (s == maxp) { ld[s] = d; li[s] = j; }
          float m = -INFINITY; int mp = 0;
          #pragma unroll
          for (int s = 0; s < KEEP; s++) if (ld[s] > m) { m = ld[s]; mp = s; }
          maxv = m; maxp = mp;
        }
      }
    }
  }
  if (t < QI) {
    const size_t base = ((size_t)(qbase + t) * NSLICE + slice) * KEEP;
    #pragma unroll
    for (int s = 0; s < KEEP; s++) cand_out[base + s] = li[s];
  }
}

// ---------------------------------------------------------------------------
// KNN refine (np-fp32): one block per query; threads 0..191 re-score one
// candidate EXACTLY as round 4 (sequential fp32 fma chain; locked rounding),
// rank by (d, index) among all 192 — reproducing top_k's stable order.
template<int C>
__global__ void knn_refine_np(const float* __restrict__ feat, const float* __restrict__ sq,
                              const int* __restrict__ cand, int* __restrict__ idx_out) {
  __shared__ float ds[CAND_TOT];
  __shared__ int   js[CAND_TOT];
  __shared__ float xqs[C];
  const int q = blockIdx.x;
  const int t = threadIdx.x;
  for (int v = t; v < C; v += 256) xqs[v] = feat[(size_t)q * C + v];
  __syncthreads();
  float d = 0.f; int j = 0x7fffffff;
  if (t < CAND_TOT) {
    j = cand[(size_t)q * CAND_TOT + t];
    const float* xj = feat + (size_t)j * C;
    float g = 0.f;
    for (int c = 0; c < C; c++) g = fmaf(xqs[c], xj[c], g);
    d = __fsub_rn(__fadd_rn(sq[q], sq[j]), __fmul_rn(2.f, g));
    ds[t] = d; js[t] = j;
  }
  __syncthreads();
  if (t < CAND_TOT) {
    int rank = 0;
    for (int m = 0; m < CAND_TOT; m++) {
      float dm = ds[m]; int jm = js[m];
      if (dm < d || (dm == d && jm < j)) rank++;
    }
    if (rank < KNN_K) idx_out[(size_t)q * KNN_K + rank] = j;
  }
}

// ---------------------------------------------------------------------------
// P[n][ch] = b[ch] + x[n]@(Wtop - Wbot)[:,ch];  Q[n][ch] = x[n]@Wbot[:,ch].
// One thread per (n,ch), fp64 accumulation. W is (2C x 128) row-major.
template<int C>
__global__ void pq_kernel(const float* __restrict__ feat, const float* __restrict__ W,
                          const float* __restrict__ b, float* __restrict__ P,
                          float* __restrict__ Q) {
  int gid = blockIdx.x * 256 + threadIdx.x;   // N*128 threads
  int n = gid >> 7, ch = gid & 127;
  const float* xr = feat + (size_t)n * C;
  double p = (double)b[ch], q = 0.0;
  for (int d = 0; d < C; d++) {
    double xv = (double)xr[d];
    p += xv * (double)W[(size_t)d * HDIM + ch];            // Wtop
    q += xv * (double)W[(size_t)(C + d) * HDIM + ch];      // Wbot
  }
  P[gid] = (float)(p - q);
  Q[gid] = (float)q;
}

// ---------------------------------------------------------------------------
// h[n,k,ch] = relu(P[n,ch] + Q[idx[n,k],ch]); per-(n,ch) max/min over k;
// per-channel fp64 sum/sumsq via block reduction + one double atomic per ch.
__global__ void edge_gather2(const float* __restrict__ P, const float* __restrict__ Q,
                             const int* __restrict__ idx, float* __restrict__ hmax,
                             float* __restrict__ hmin, double* __restrict__ stats) {
  __shared__ double red0[256];
  __shared__ double red1[256];
  const int t = threadIdx.x;           // 256 = 2 half-threads x 128 ch
  const int ch = t & 127, half = t >> 7;
  const size_t nb = (size_t)blockIdx.x * 16 + (size_t)half * 8;
  double s = 0.0, s2 = 0.0;
  for (int u = 0; u < 8; u++) {
    const size_t n = nb + u;
    double p = (double)P[n * 128 + ch];
    double mx = -1.0e300, mn = 1.0e300;
    for (int k = 0; k < KNN_K; k++) {
      int j = idx[n * KNN_K + k];
      double h = p + (double)Q[(size_t)j * 128 + ch];
      h = h > 0.0 ? h : 0.0;
      mx = h > mx ? h : mx;
      mn = h < mn ? h : mn;
      s += h; s2 += h * h;
    }
    hmax[n * 128 + ch] = (float)mx;
    hmin[n * 128 + ch] = (float)mn;
  }
  red0[t] = s; red1[t] = s2;
  __syncthreads();
  if (t < 128) {
    atomicAdd(&stats[ch],       red0[t] + red0[t + 128]);
    atomicAdd(&stats[128 + ch], red1[t] + red1[t + 128]);
  }
}

__global__ void zero_stats_d(double* __restrict__ stats) {
  stats[threadIdx.x] = 0.0;   // 256 doubles
}

__global__ void bn_finalize_d(const double* __restrict__ stats, const float* __restrict__ g,
                              const float* __restrict__ beta, double* __restrict__ ss) {
  int ch = threadIdx.x;  // 128
  const double inv = 1.0 / ((double)N_PTS * (double)KNN_K);
  double mu = stats[ch] * inv;
  double var = stats[128 + ch] * inv - mu * mu;
  double sc = (double)g[ch] / sqrt(var + 1e-5);
  ss[ch] = sc;
  ss[128 + ch] = (double)beta[ch] - mu * sc;
}

// out = (sc>=0 ? hmax : hmin)*sc + shift  == max_k of the normalized h.
__global__ void ec_out_d(const float* __restrict__ hmax, const float* __restrict__ hmin,
                         const double* __restrict__ ss, float* __restrict__ h_f) {
  size_t i = (size_t)blockIdx.x * 256 + threadIdx.x;
  int ch = (int)(i & 127);
  double sc = ss[ch];
  double v = sc >= 0.0 ? (double)hmax[i] : (double)hmin[i];
  h_f[i] = (float)(v * sc + ss[128 + ch]);
}

// ---------------------------------------------------------------------------
// Head, naive fp64: T = relu(relu(h2) @ lw1 + lb1); out = T @ lw2 + lb2.
__global__ void head1_kernel(const float* __restrict__ h2, const float* __restrict__ lw1,
                             const float* __restrict__ lb1, float* __restrict__ T) {
  int gid = blockIdx.x * 256 + threadIdx.x;  // N*64
  int n = gid >> 6, hc = gid & 63;
  const float* hr = h2 + (size_t)n * 128;
  double a = (double)lb1[hc];
  for (int d = 0; d < 128; d++) {
    double v = (double)hr[d];
    v = v > 0.0 ? v : 0.0;
    a += v * (double)lw1[(size_t)d * 64 + hc];
  }
  T[gid] = (float)(a > 0.0 ? a : 0.0);
}

__global__ void head2_kernel(const float* __restrict__ T, const float* __restrict__ lw2,
                             const float* __restrict__ lb2, float* __restrict__ out) {
  int gid = blockIdx.x * 256 + threadIdx.x;  // N*64
  int n = gid >> 6, oc = gid & 63;
  const float* tr = T + (size_t)n * 64;
  double a = (double)lb2[oc];
  for (int d = 0; d < 64; d++) a += (double)tr[d] * (double)lw2[(size_t)d * 64 + oc];
  out[gid] = (float)a;
}

// ---------------------------------------------------------------------------
extern "C" void kernel_launch(void* const* d_in, const int* in_sizes, int n_in,
                              void* d_out, int out_size, void* d_ws, size_t ws_size,
                              hipStream_t stream) {
  (void)in_sizes; (void)n_in; (void)out_size; (void)ws_size;
  const float* x     = (const float*)d_in[0];
  const float* W1    = (const float*)d_in[1];
  const float* b1    = (const float*)d_in[2];
  const float* g1    = (const float*)d_in[3];
  const float* beta1 = (const float*)d_in[4];
  const float* W2    = (const float*)d_in[5];
  const float* b2    = (const float*)d_in[6];
  const float* g2    = (const float*)d_in[7];
  const float* beta2 = (const float*)d_in[8];
  const float* lw1   = (const float*)d_in[9];
  const float* lb1   = (const float*)d_in[10];
  const float* lw2   = (const float*)d_in[11];
  const float* lb2   = (const float*)d_in[12];
  float* out = (float*)d_out;

  char* w = (char*)d_ws;
  size_t off = 0;
  auto alloc = [&](size_t bytes) { char* p = w + off; off += (bytes + 255) & ~(size_t)255; return p; };
  float*  sq    = (float*) alloc(N_PTS * 4);                      //  64 KB
  int*    cand  = (int*)   alloc((size_t)N_PTS * CAND_TOT * 4);   // 12.6 MB
  int*    idx   = (int*)   alloc((size_t)N_PTS * KNN_K * 4);      //    2 MB
  float*  P     = (float*) alloc((size_t)N_PTS * HDIM * 4);       //    8 MB
  float*  Q     = (float*) alloc((size_t)N_PTS * HDIM * 4);       //    8 MB
  float*  hmax  = (float*) alloc((size_t)N_PTS * HDIM * 4);       //    8 MB
  float*  hmin  = (float*) alloc((size_t)N_PTS * HDIM * 4);       //    8 MB
  double* stats = (double*)alloc(2 * HDIM * 8);                   //    2 KB
  double* ss    = (double*)alloc(2 * HDIM * 8);                   //    2 KB
  float*  h1f   = (float*) alloc((size_t)N_PTS * HDIM * 4);       //    8 MB
  float*  h2f   = P;                                              // reuse (P dead after gather2)
  float*  T     = Q;                                              // reuse (Q dead after gather2)

  // ---- stage 1: knn on x (C=64), np-fp32-exact selection ----
  sqnorm_np_kernel<64><<<N_PTS / 256, 256, 0, stream>>>(x, sq);
  knn_cand_kernel<64><<<dim3(N_PTS / 64, NSLICE), 256, 0, stream>>>(x, sq, cand);
  knn_refine_np<64><<<N_PTS, 256, 0, stream>>>(x, sq, cand, idx);

  // ---- edge conv 1 (fp64) ----
  pq_kernel<64><<<N_PTS * 128 / 256, 256, 0, stream>>>(x, W1, b1, P, Q);
  zero_stats_d<<<1, 256, 0, stream>>>(stats);
  edge_gather2<<<N_PTS / 16, 256, 0, stream>>>(P, Q, idx, hmax, hmin, stats);
  bn_finalize_d<<<1, 128, 0, stream>>>(stats, g1, beta1, ss);
  ec_out_d<<<N_PTS * HDIM / 256, 256, 0, stream>>>(hmax, hmin, ss, h1f);

  // ---- stage 2: knn on h1 (C=128), np-fp32-exact selection ----
  sqnorm_np_kernel<128><<<N_PTS / 256, 256, 0, stream>>>(h1f, sq);
  knn_cand_kernel<128><<<dim3(N_PTS / 64, NSLICE), 256, 0, stream>>>(h1f, sq, cand);
  knn_refine_np<128><<<N_PTS, 256, 0, stream>>>(h1f, sq, cand, idx);

  // ---- edge conv 2 (fp64) ----
  pq_kernel<128><<<N_PTS * 128 / 256, 256, 0, stream>>>(h1f, W2, b2, P, Q);
  zero_stats_d<<<1, 256, 0, stream>>>(stats);
  edge_gather2<<<N_PTS / 16, 256, 0, stream>>>(P, Q, idx, hmax, hmin, stats);
  bn_finalize_d<<<1, 128, 0, stream>>>(stats, g2, beta2, ss);
  ec_out_d<<<N_PTS * HDIM / 256, 256, 0, stream>>>(hmax, hmin, ss, h2f);

  // ---- head (fp64) ----
  head1_kernel<<<N_PTS * 64 / 256, 256, 0, stream>>>(h2f, lw1, lb1, T);
  head2_kernel<<<N_PTS * 64 / 256, 256, 0, stream>>>(T, lw2, lb2, out);
}

// Round 6
// 4774.297 us; speedup vs baseline: 3.7085x; 3.7085x over previous
//
#include <hip/hip_runtime.h>
#include <hip/hip_bf16.h>
#include <math.h>

#define N_PTS 16384
#define KNN_K 32
#define KEEP 40                    // per-stream register top-K
#define STREAMS 8                  // selection streams per query
#define CAND_TOT (KEEP * STREAMS)  // 320 candidates/query into np-exact refine
#define HDIM 128

typedef __attribute__((ext_vector_type(8))) short    bf16x8;
typedef __attribute__((ext_vector_type(8))) unsigned short ushort8v;
typedef __attribute__((ext_vector_type(4))) float    f32x4;

// ---------------------------------------------------------------------------
// numpy-pairwise fp32 sum of squares per row (np.sum(x*x, axis=1) replica).
template<int C>
__global__ void sqnorm_np_kernel(const float* __restrict__ feat, float* __restrict__ sq) {
  int r = blockIdx.x * 256 + threadIdx.x;
  if (r >= N_PTS) return;
  const float* xr = feat + (size_t)r * C;
  float acc[8];
  #pragma unroll
  for (int j = 0; j < 8; j++) acc[j] = __fmul_rn(xr[j], xr[j]);
  for (int i = 8; i < C; i += 8) {
    #pragma unroll
    for (int j = 0; j < 8; j++)
      acc[j] = __fadd_rn(acc[j], __fmul_rn(xr[i + j], xr[i + j]));
  }
  float s01 = __fadd_rn(acc[0], acc[1]);
  float s23 = __fadd_rn(acc[2], acc[3]);
  float s45 = __fadd_rn(acc[4], acc[5]);
  float s67 = __fadd_rn(acc[6], acc[7]);
  sq[r] = __fadd_rn(__fadd_rn(s01, s23), __fadd_rn(s45, s67));
}

// ---------------------------------------------------------------------------
// hi/lo bf16 split: hi = bf16(x), lo = bf16(x - float(hi)).
__global__ void split_bf16_kernel(const float* __restrict__ x, unsigned short* __restrict__ hi,
                                  unsigned short* __restrict__ lo, int total) {
  int i = blockIdx.x * 256 + threadIdx.x;
  if (i >= total) return;
  float v = x[i];
  __hip_bfloat16 h = __float2bfloat16(v);
  float hf = __bfloat162float(h);
  __hip_bfloat16 l = __float2bfloat16(v - hf);
  hi[i] = *(unsigned short*)&h;
  lo[i] = *(unsigned short*)&l;
}

// ---------------------------------------------------------------------------
// KNN candidate pass: 32 queries/block vs all candidates in 32-wide tiles.
// Split-bf16 MFMA (hi*hi + hi*lo + lo*hi) computes the Gram tile; Dist tile
// (sq_j - 2G, per-query-monotone in true distance) goes to LDS; ALL 256
// threads run selection: thread (q = t&31, s = t>>5) scans cols s*4..s*4+3
// of each tile keeping a register top-40. Union of 8 disjoint streams/query
// contains the np-fp32 top-32 (stream-rank <= global rank; KEEP margin >>
// split-bf16 GEMM error ~1e-4 vs rank-gap ~0.05).
template<int C>
__launch_bounds__(256)
__global__ void knn_cand_mfma(const unsigned short* __restrict__ xhi,
                              const unsigned short* __restrict__ xlo,
                              const float* __restrict__ sq,
                              int* __restrict__ cand_out) {
  constexpr int QI = 32, NJ = 32;
  constexpr int LROW = C + 8;        // +8 bf16 pad: frag b128 reads 2-way (free)
  __shared__ unsigned short Ahi[QI * LROW], Alo[QI * LROW];
  __shared__ unsigned short Bhi[NJ * LROW], Blo[NJ * LROW];
  __shared__ float Dist[QI * (NJ + 1)];

  const int t = threadIdx.x;
  const int qbase = blockIdx.x * QI;
  const int wv = t >> 6, lane = t & 63;
  const int qd = lane >> 4, l16 = lane & 15;
  const int mi = (wv & 1) * 16, ni = (wv >> 1) * 16;   // wave's 16x16 out tile

  // stage the 32 query rows (hi+lo) once
  for (int v = t; v < QI * C / 8; v += 256) {
    int r = v / (C / 8), c8 = v % (C / 8);
    size_t g = (size_t)(qbase + r) * C + c8 * 8;
    *(ushort8v*)&Ahi[r * LROW + c8 * 8] = *(const ushort8v*)&xhi[g];
    *(ushort8v*)&Alo[r * LROW + c8 * 8] = *(const ushort8v*)&xlo[g];
  }

  // per-thread top-KEEP state (registers; unrolled access only)
  float ld[KEEP]; int li[KEEP];
  #pragma unroll
  for (int s = 0; s < KEEP; s++) { ld[s] = INFINITY; li[s] = 0; }
  float maxv = INFINITY; int maxp = 0;

  const int aoff = (mi + l16) * LROW + qd * 8;   // A-frag: row=query m, k=qd*8+j
  const int boff = (ni + l16) * LROW + qd * 8;   // B-frag: col=cand n,  k=qd*8+j
  const int selq = t & 31, sels = t >> 5;
  const int gi = qbase + selq;

  for (int j0 = 0; j0 < N_PTS; j0 += NJ) {
    __syncthreads();               // prev selection done: B/Dist free
    for (int v = t; v < NJ * C / 8; v += 256) {
      int r = v / (C / 8), c8 = v % (C / 8);
      size_t g = (size_t)(j0 + r) * C + c8 * 8;
      *(ushort8v*)&Bhi[r * LROW + c8 * 8] = *(const ushort8v*)&xhi[g];
      *(ushort8v*)&Blo[r * LROW + c8 * 8] = *(const ushort8v*)&xlo[g];
    }
    __syncthreads();

    f32x4 acc = {0.f, 0.f, 0.f, 0.f};
    #pragma unroll
    for (int kc = 0; kc < C; kc += 32) {
      bf16x8 ah = *(const bf16x8*)&Ahi[aoff + kc];
      bf16x8 al = *(const bf16x8*)&Alo[aoff + kc];
      bf16x8 bh = *(const bf16x8*)&Bhi[boff + kc];
      bf16x8 bl = *(const bf16x8*)&Blo[boff + kc];
      acc = __builtin_amdgcn_mfma_f32_16x16x32_bf16(ah, bh, acc, 0, 0, 0);
      acc = __builtin_amdgcn_mfma_f32_16x16x32_bf16(ah, bl, acc, 0, 0, 0);
      acc = __builtin_amdgcn_mfma_f32_16x16x32_bf16(al, bh, acc, 0, 0, 0);
    }
    // D layout: col=lane&15, row=qd*4+reg  ->  Dist[m][n] = sq_j - 2*G
    {
      float sj = sq[j0 + ni + l16];
      #pragma unroll
      for (int r = 0; r < 4; r++)
        Dist[(mi + qd * 4 + r) * (NJ + 1) + ni + l16] = sj - 2.f * acc[r];
    }
    __syncthreads();
    // selection: 4 columns per thread per tile
    #pragma unroll
    for (int cc = 0; cc < 4; cc++) {
      int c = sels * 4 + cc;
      float d = Dist[selq * (NJ + 1) + c];
      int j = j0 + c;
      if (d < maxv && j != gi) {
        #pragma unroll
        for (int s = 0; s < KEEP; s++) if (s == maxp) { ld[s] = d; li[s] = j; }
        float m = -INFINITY; int mp = 0;
        #pragma unroll
        for (int s = 0; s < KEEP; s++) if (ld[s] > m) { m = ld[s]; mp = s; }
        maxv = m; maxp = mp;
      }
    }
  }
  const size_t base = ((size_t)gi * STREAMS + sels) * KEEP;
  #pragma unroll
  for (int s = 0; s < KEEP; s++) cand_out[base + s] = li[s];
}

// ---------------------------------------------------------------------------
// KNN refine (np-fp32-exact): one block per query, 320 threads = one per
// candidate. Sequential fp32 fma chain + locked-rounding distance formula;
// rank by (d, index) = top_k's stable order. Streams are disjoint -> no dups.
template<int C>
__global__ void knn_refine_np(const float* __restrict__ feat, const float* __restrict__ sq,
                              const int* __restrict__ cand, int* __restrict__ idx_out) {
  __shared__ float ds[CAND_TOT];
  __shared__ int   js[CAND_TOT];
  __shared__ float xqs[C];
  const int q = blockIdx.x;
  const int t = threadIdx.x;  // 320
  for (int v = t; v < C; v += CAND_TOT) xqs[v] = feat[(size_t)q * C + v];
  __syncthreads();
  int j = cand[(size_t)q * CAND_TOT + t];
  const float* xj = feat + (size_t)j * C;
  float g = 0.f;
  for (int c = 0; c < C; c++) g = fmaf(xqs[c], xj[c], g);
  float d = __fsub_rn(__fadd_rn(sq[q], sq[j]), __fmul_rn(2.f, g));
  ds[t] = d; js[t] = j;
  __syncthreads();
  int rank = 0;
  for (int m = 0; m < CAND_TOT; m++) {
    float dm = ds[m]; int jm = js[m];
    if (dm < d || (dm == d && jm < j)) rank++;
  }
  if (rank < KNN_K) idx_out[(size_t)q * KNN_K + rank] = j;
}

// ---------------------------------------------------------------------------
// P[n][ch] = b[ch] + x[n]@(Wtop - Wbot)[:,ch];  Q[n][ch] = x[n]@Wbot[:,ch].
template<int C>
__global__ void pq_kernel(const float* __restrict__ feat, const float* __restrict__ W,
                          const float* __restrict__ b, float* __restrict__ P,
                          float* __restrict__ Q) {
  int gid = blockIdx.x * 256 + threadIdx.x;   // N*128 threads
  int n = gid >> 7, ch = gid & 127;
  const float* xr = feat + (size_t)n * C;
  double p = (double)b[ch], q = 0.0;
  for (int d = 0; d < C; d++) {
    double xv = (double)xr[d];
    p += xv * (double)W[(size_t)d * HDIM + ch];
    q += xv * (double)W[(size_t)(C + d) * HDIM + ch];
  }
  P[gid] = (float)(p - q);
  Q[gid] = (float)q;
}

// ---------------------------------------------------------------------------
__global__ void edge_gather2(const float* __restrict__ P, const float* __restrict__ Q,
                             const int* __restrict__ idx, float* __restrict__ hmax,
                             float* __restrict__ hmin, double* __restrict__ stats) {
  __shared__ double red0[256];
  __shared__ double red1[256];
  const int t = threadIdx.x;
  const int ch = t & 127, half = t >> 7;
  const size_t nb = (size_t)blockIdx.x * 16 + (size_t)half * 8;
  double s = 0.0, s2 = 0.0;
  for (int u = 0; u < 8; u++) {
    const size_t n = nb + u;
    double p = (double)P[n * 128 + ch];
    double mx = -1.0e300, mn = 1.0e300;
    for (int k = 0; k < KNN_K; k++) {
      int j = idx[n * KNN_K + k];
      double h = p + (double)Q[(size_t)j * 128 + ch];
      h = h > 0.0 ? h : 0.0;
      mx = h > mx ? h : mx;
      mn = h < mn ? h : mn;
      s += h; s2 += h * h;
    }
    hmax[n * 128 + ch] = (float)mx;
    hmin[n * 128 + ch] = (float)mn;
  }
  red0[t] = s; red1[t] = s2;
  __syncthreads();
  if (t < 128) {
    atomicAdd(&stats[ch],       red0[t] + red0[t + 128]);
    atomicAdd(&stats[128 + ch], red1[t] + red1[t + 128]);
  }
}

__global__ void zero_stats_d(double* __restrict__ stats) {
  stats[threadIdx.x] = 0.0;
}

__global__ void bn_finalize_d(const double* __restrict__ stats, const float* __restrict__ g,
                              const float* __restrict__ beta, double* __restrict__ ss) {
  int ch = threadIdx.x;
  const double inv = 1.0 / ((double)N_PTS * (double)KNN_K);
  double mu = stats[ch] * inv;
  double var = stats[128 + ch] * inv - mu * mu;
  double sc = (double)g[ch] / sqrt(var + 1e-5);
  ss[ch] = sc;
  ss[128 + ch] = (double)beta[ch] - mu * sc;
}

__global__ void ec_out_d(const float* __restrict__ hmax, const float* __restrict__ hmin,
                         const double* __restrict__ ss, float* __restrict__ h_f) {
  size_t i = (size_t)blockIdx.x * 256 + threadIdx.x;
  int ch = (int)(i & 127);
  double sc = ss[ch];
  double v = sc >= 0.0 ? (double)hmax[i] : (double)hmin[i];
  h_f[i] = (float)(v * sc + ss[128 + ch]);
}

// ---------------------------------------------------------------------------
__global__ void head1_kernel(const float* __restrict__ h2, const float* __restrict__ lw1,
                             const float* __restrict__ lb1, float* __restrict__ T) {
  int gid = blockIdx.x * 256 + threadIdx.x;
  int n = gid >> 6, hc = gid & 63;
  const float* hr = h2 + (size_t)n * 128;
  double a = (double)lb1[hc];
  for (int d = 0; d < 128; d++) {
    double v = (double)hr[d];
    v = v > 0.0 ? v : 0.0;
    a += v * (double)lw1[(size_t)d * 64 + hc];
  }
  T[gid] = (float)(a > 0.0 ? a : 0.0);
}

__global__ void head2_kernel(const float* __restrict__ T, const float* __restrict__ lw2,
                             const float* __restrict__ lb2, float* __restrict__ out) {
  int gid = blockIdx.x * 256 + threadIdx.x;
  int n = gid >> 6, oc = gid & 63;
  const float* tr = T + (size_t)n * 64;
  double a = (double)lb2[oc];
  for (int d = 0; d < 64; d++) a += (double)tr[d] * (double)lw2[(size_t)d * 64 + oc];
  out[gid] = (float)a;
}

// ---------------------------------------------------------------------------
extern "C" void kernel_launch(void* const* d_in, const int* in_sizes, int n_in,
                              void* d_out, int out_size, void* d_ws, size_t ws_size,
                              hipStream_t stream) {
  (void)in_sizes; (void)n_in; (void)out_size; (void)ws_size;
  const float* x     = (const float*)d_in[0];
  const float* W1    = (const float*)d_in[1];
  const float* b1    = (const float*)d_in[2];
  const float* g1    = (const float*)d_in[3];
  const float* beta1 = (const float*)d_in[4];
  const float* W2    = (const float*)d_in[5];
  const float* b2    = (const float*)d_in[6];
  const float* g2    = (const float*)d_in[7];
  const float* beta2 = (const float*)d_in[8];
  const float* lw1   = (const float*)d_in[9];
  const float* lb1   = (const float*)d_in[10];
  const float* lw2   = (const float*)d_in[11];
  const float* lb2   = (const float*)d_in[12];
  float* out = (float*)d_out;

  char* w = (char*)d_ws;
  size_t off = 0;
  auto alloc = [&](size_t bytes) { char* p = w + off; off += (bytes + 255) & ~(size_t)255; return p; };
  float*  sq    = (float*) alloc(N_PTS * 4);
  int*    cand  = (int*)   alloc((size_t)N_PTS * CAND_TOT * 4);     // 21 MB
  int*    idx   = (int*)   alloc((size_t)N_PTS * KNN_K * 4);        //  2 MB
  unsigned short* xhi = (unsigned short*)alloc((size_t)N_PTS * HDIM * 2);  // 4.2 MB
  unsigned short* xlo = (unsigned short*)alloc((size_t)N_PTS * HDIM * 2);  // 4.2 MB
  float*  P     = (float*) alloc((size_t)N_PTS * HDIM * 4);
  float*  Q     = (float*) alloc((size_t)N_PTS * HDIM * 4);
  float*  hmax  = (float*) alloc((size_t)N_PTS * HDIM * 4);
  float*  hmin  = (float*) alloc((size_t)N_PTS * HDIM * 4);
  double* stats = (double*)alloc(2 * HDIM * 8);
  double* ss    = (double*)alloc(2 * HDIM * 8);
  float*  h1f   = (float*) alloc((size_t)N_PTS * HDIM * 4);
  float*  h2f   = P;        // reuse (P dead after gather2)
  float*  T     = Q;        // reuse (Q dead after gather2)

  // ---- stage 1: knn on x (C=64) ----
  sqnorm_np_kernel<64><<<N_PTS / 256, 256, 0, stream>>>(x, sq);
  split_bf16_kernel<<<N_PTS * 64 / 256, 256, 0, stream>>>(x, xhi, xlo, N_PTS * 64);
  knn_cand_mfma<64><<<N_PTS / 32, 256, 0, stream>>>(xhi, xlo, sq, cand);
  knn_refine_np<64><<<N_PTS, CAND_TOT, 0, stream>>>(x, sq, cand, idx);

  // ---- edge conv 1 (fp64) ----
  pq_kernel<64><<<N_PTS * 128 / 256, 256, 0, stream>>>(x, W1, b1, P, Q);
  zero_stats_d<<<1, 256, 0, stream>>>(stats);
  edge_gather2<<<N_PTS / 16, 256, 0, stream>>>(P, Q, idx, hmax, hmin, stats);
  bn_finalize_d<<<1, 128, 0, stream>>>(stats, g1, beta1, ss);
  ec_out_d<<<N_PTS * HDIM / 256, 256, 0, stream>>>(hmax, hmin, ss, h1f);

  // ---- stage 2: knn on h1 (C=128) ----
  sqnorm_np_kernel<128><<<N_PTS / 256, 256, 0, stream>>>(h1f, sq);
  split_bf16_kernel<<<N_PTS * 128 / 256, 256, 0, stream>>>(h1f, xhi, xlo, N_PTS * 128);
  knn_cand_mfma<128><<<N_PTS / 32, 256, 0, stream>>>(xhi, xlo, sq, cand);
  knn_refine_np<128><<<N_PTS, CAND_TOT, 0, stream>>>(h1f, sq, cand, idx);

  // ---- edge conv 2 (fp64) ----
  pq_kernel<128><<<N_PTS * 128 / 256, 256, 0, stream>>>(h1f, W2, b2, P, Q);
  zero_stats_d<<<1, 256, 0, stream>>>(stats);
  edge_gather2<<<N_PTS / 16, 256, 0, stream>>>(P, Q, idx, hmax, hmin, stats);
  bn_finalize_d<<<1, 128, 0, stream>>>(stats, g2, beta2, ss);
  ec_out_d<<<N_PTS * HDIM / 256, 256, 0, stream>>>(hmax, hmin, ss, h2f);

  // ---- head (fp64) ----
  head1_kernel<<<N_PTS * 64 / 256, 256, 0, stream>>>(h2f, lw1, lb1, T);
  head2_kernel<<<N_PTS * 64 / 256, 256, 0, stream>>>(T, lw2, lb2, out);
}

// Round 8
// 3484.166 us; speedup vs baseline: 5.0817x; 1.3703x over previous
//
#include <hip/hip_runtime.h>
#include <hip/hip_bf16.h>
#include <math.h>

#define N_PTS 16384
#define KNN_K 32
#define CAP 448            // per-query filtered candidate list capacity
#define HDIM 128

typedef __attribute__((ext_vector_type(8))) short bf16x8;
typedef __attribute__((ext_vector_type(4))) float f32x4;

// ---------------------------------------------------------------------------
// numpy-pairwise fp32 sum of squares per row (np.sum(x*x, axis=1) replica).
template<int C>
__global__ void sqnorm_np_kernel(const float* __restrict__ feat, float* __restrict__ sq) {
  int r = blockIdx.x * 256 + threadIdx.x;
  if (r >= N_PTS) return;
  const float* xr = feat + (size_t)r * C;
  float acc[8];
  #pragma unroll
  for (int j = 0; j < 8; j++) acc[j] = __fmul_rn(xr[j], xr[j]);
  for (int i = 8; i < C; i += 8) {
    #pragma unroll
    for (int j = 0; j < 8; j++)
      acc[j] = __fadd_rn(acc[j], __fmul_rn(xr[i + j], xr[i + j]));
  }
  float s01 = __fadd_rn(acc[0], acc[1]);
  float s23 = __fadd_rn(acc[2], acc[3]);
  float s45 = __fadd_rn(acc[4], acc[5]);
  float s67 = __fadd_rn(acc[6], acc[7]);
  sq[r] = __fadd_rn(__fadd_rn(s01, s23), __fadd_rn(s45, s67));
}

// ---------------------------------------------------------------------------
// hi/lo bf16 split: hi = bf16(x), lo = bf16(x - float(hi)).
__global__ void split_bf16_kernel(const float* __restrict__ x, unsigned short* __restrict__ hi,
                                  unsigned short* __restrict__ lo, int total) {
  int i = blockIdx.x * 256 + threadIdx.x;
  if (i >= total) return;
  float v = x[i];
  __hip_bfloat16 h = __float2bfloat16(v);
  float hf = __bfloat162float(h);
  __hip_bfloat16 l = __float2bfloat16(v - hf);
  hi[i] = *(unsigned short*)&h;
  lo[i] = *(unsigned short*)&l;
}

// ---------------------------------------------------------------------------
// KNN pass A (tau): 64 queries/block, 8 waves each own a 16x16 MFMA tile of
// the SPLIT-bf16 distance (identical 3-MFMA arithmetic to the filter pass ->
// bit-identical d values). Each lane keeps the top-2 (smallest d = sq_j - 2G)
// of its stream; per query the 32 disjoint streams' top-2 form a 64-value
// union U. tau = 33rd-smallest(U) + margin. Guarantee: 33rd-of-subset >=
// d_(33) >= d_(32); margin covers only split-vs-np error (~1e-3).
template<int C>
__launch_bounds__(512)
__global__ void knn_tau(const unsigned short* __restrict__ xhi,
                        const unsigned short* __restrict__ xlo,
                        const float* __restrict__ sq,
                        float margin, float* __restrict__ tau) {
  constexpr int KC = C / 32;
  __shared__ float tred[64][65];   // [query][stream]=t0, [query][32+stream]=t1
  const int t = threadIdx.x;
  const int qbase = blockIdx.x * 64;
  const int wv = t >> 6, lane = t & 63, qd = lane >> 4, l16 = lane & 15;
  const int mi = (wv & 3) * 16, ni = (wv >> 2) * 16;

  bf16x8 ah[KC], al[KC];
  #pragma unroll
  for (int kc = 0; kc < KC; kc++) {
    size_t o = (size_t)(qbase + mi + l16) * C + kc * 32 + qd * 8;
    ah[kc] = *(const bf16x8*)&xhi[o];
    al[kc] = *(const bf16x8*)&xlo[o];
  }
  int qr[4];
  #pragma unroll
  for (int r = 0; r < 4; r++) qr[r] = qbase + mi + qd * 4 + r;

  float t0[4], t1[4];
  #pragma unroll
  for (int r = 0; r < 4; r++) { t0[r] = INFINITY; t1[r] = INFINITY; }

  for (int j0 = 0; j0 < N_PTS; j0 += 32) {
    const int j = j0 + ni + l16;
    f32x4 acc = {0.f, 0.f, 0.f, 0.f};
    #pragma unroll
    for (int kc = 0; kc < KC; kc++) {
      size_t o = (size_t)j * C + kc * 32 + qd * 8;
      bf16x8 bh = *(const bf16x8*)&xhi[o];
      bf16x8 bl = *(const bf16x8*)&xlo[o];
      acc = __builtin_amdgcn_mfma_f32_16x16x32_bf16(ah[kc], bh, acc, 0, 0, 0);
      acc = __builtin_amdgcn_mfma_f32_16x16x32_bf16(ah[kc], bl, acc, 0, 0, 0);
      acc = __builtin_amdgcn_mfma_f32_16x16x32_bf16(al[kc], bh, acc, 0, 0, 0);
    }
    const float sj = sq[j];
    #pragma unroll
    for (int r = 0; r < 4; r++) {
      float d = fmaf(-2.f, acc[r], sj);
      if (d < t1[r] && j != qr[r]) {     // self-excluded: pigeonhole stays valid
        bool lt = d < t0[r];
        t1[r] = lt ? t0[r] : d;
        t0[r] = lt ? d : t0[r];
      }
    }
  }
  const int s = ni + l16;                // stream id 0..31
  #pragma unroll
  for (int r = 0; r < 4; r++) {
    tred[mi + qd * 4 + r][s]      = t0[r];
    tred[mi + qd * 4 + r][32 + s] = t1[r];
  }
  __syncthreads();
  // 33rd-smallest of the 64-value union, tie-broken total order.
  // 8 threads per query, each ranks 8 of the 64 values.
  const int tq = t >> 3, i0 = (t & 7) * 8;
  #pragma unroll
  for (int ii = 0; ii < 8; ii++) {
    const int i = i0 + ii;
    const float vi = tred[tq][i];
    int rank = 0;
    for (int m = 0; m < 64; m++) {
      float vm = tred[tq][m];
      rank += (vm < vi || (vm == vi && m < i)) ? 1 : 0;
    }
    if (rank == 32) tau[qbase + tq] = vi + margin;   // exactly one writer
  }
}

// ---------------------------------------------------------------------------
// KNN pass B (filter): identical split-bf16 MFMA distances; keep j if
// d <= tau[q]. Grid (qtile, jslice): 1024 blocks x 8 waves. No LDS.
template<int C>
__launch_bounds__(512)
__global__ void knn_filter(const unsigned short* __restrict__ xhi,
                           const unsigned short* __restrict__ xlo,
                           const float* __restrict__ sq,
                           const float* __restrict__ tau,
                           int* __restrict__ cnt, int* __restrict__ list) {
  constexpr int KC = C / 32;
  constexpr int JSPAN = N_PTS / 4;
  const int t = threadIdx.x;
  const int qbase = blockIdx.x * 64;
  const int jbase = blockIdx.y * JSPAN;
  const int wv = t >> 6, lane = t & 63, qd = lane >> 4, l16 = lane & 15;
  const int mi = (wv & 3) * 16, ni = (wv >> 2) * 16;

  bf16x8 ah[KC], al[KC];
  #pragma unroll
  for (int kc = 0; kc < KC; kc++) {
    size_t o = (size_t)(qbase + mi + l16) * C + kc * 32 + qd * 8;
    ah[kc] = *(const bf16x8*)&xhi[o];
    al[kc] = *(const bf16x8*)&xlo[o];
  }
  int qr[4]; float tq[4];
  #pragma unroll
  for (int r = 0; r < 4; r++) {
    qr[r] = qbase + mi + qd * 4 + r;
    tq[r] = tau[qr[r]];
  }

  for (int j0 = jbase; j0 < jbase + JSPAN; j0 += 32) {
    const int j = j0 + ni + l16;
    f32x4 acc = {0.f, 0.f, 0.f, 0.f};
    #pragma unroll
    for (int kc = 0; kc < KC; kc++) {
      size_t o = (size_t)j * C + kc * 32 + qd * 8;
      bf16x8 bh = *(const bf16x8*)&xhi[o];
      bf16x8 bl = *(const bf16x8*)&xlo[o];
      acc = __builtin_amdgcn_mfma_f32_16x16x32_bf16(ah[kc], bh, acc, 0, 0, 0);
      acc = __builtin_amdgcn_mfma_f32_16x16x32_bf16(ah[kc], bl, acc, 0, 0, 0);
      acc = __builtin_amdgcn_mfma_f32_16x16x32_bf16(al[kc], bh, acc, 0, 0, 0);
    }
    const float sj = sq[j];
    #pragma unroll
    for (int r = 0; r < 4; r++) {
      float d = fmaf(-2.f, acc[r], sj);
      if (d <= tq[r] && j != qr[r]) {
        int pos = atomicAdd(&cnt[qr[r]], 1);
        if (pos < CAP) list[(size_t)qr[r] * CAP + pos] = j;
      }
    }
  }
}

__global__ void zero_cnt_kernel(int* __restrict__ cnt) {
  cnt[blockIdx.x * 256 + threadIdx.x] = 0;
}

// ---------------------------------------------------------------------------
// KNN refine (np-fp32-exact, unchanged): one block/query, thread t scores
// candidate t; rank by (d, index) = top_k's stable order.
template<int C>
__global__ void knn_refine_np(const float* __restrict__ feat, const float* __restrict__ sq,
                              const int* __restrict__ cnt, const int* __restrict__ list,
                              int* __restrict__ idx_out) {
  __shared__ float ds[CAP];
  __shared__ int   js[CAP];
  __shared__ float xqs[C];
  const int q = blockIdx.x;
  const int t = threadIdx.x;  // CAP threads
  for (int v = t; v < C; v += CAP) xqs[v] = feat[(size_t)q * C + v];
  int cq = cnt[q]; if (cq > CAP) cq = CAP;
  __syncthreads();
  float d = INFINITY; int j = 0x7fffffff;
  if (t < cq) {
    j = list[(size_t)q * CAP + t];
    const float* xj = feat + (size_t)j * C;
    float g = 0.f;
    for (int c = 0; c < C; c++) g = fmaf(xqs[c], xj[c], g);
    d = __fsub_rn(__fadd_rn(sq[q], sq[j]), __fmul_rn(2.f, g));
    ds[t] = d; js[t] = j;
  }
  __syncthreads();
  if (t < cq) {
    int rank = 0;
    for (int m = 0; m < cq; m++) {
      float dm = ds[m]; int jm = js[m];
      if (dm < d || (dm == d && jm < j)) rank++;
    }
    if (rank < KNN_K) idx_out[(size_t)q * KNN_K + rank] = j;
  }
}

// ---------------------------------------------------------------------------
// P[n][ch] = b[ch] + x[n]@(Wtop - Wbot)[:,ch];  Q[n][ch] = x[n]@Wbot[:,ch].
template<int C>
__global__ void pq_kernel(const float* __restrict__ feat, const float* __restrict__ W,
                          const float* __restrict__ b, float* __restrict__ P,
                          float* __restrict__ Q) {
  int gid = blockIdx.x * 256 + threadIdx.x;   // N*128 threads
  int n = gid >> 7, ch = gid & 127;
  const float* xr = feat + (size_t)n * C;
  double p = (double)b[ch], q = 0.0;
  for (int d = 0; d < C; d++) {
    double xv = (double)xr[d];
    p += xv * (double)W[(size_t)d * HDIM + ch];
    q += xv * (double)W[(size_t)(C + d) * HDIM + ch];
  }
  P[gid] = (float)(p - q);
  Q[gid] = (float)q;
}

// ---------------------------------------------------------------------------
__global__ void edge_gather2(const float* __restrict__ P, const float* __restrict__ Q,
                             const int* __restrict__ idx, float* __restrict__ hmax,
                             float* __restrict__ hmin, double* __restrict__ stats) {
  __shared__ double red0[256];
  __shared__ double red1[256];
  const int t = threadIdx.x;
  const int ch = t & 127, half = t >> 7;
  const size_t nb = (size_t)blockIdx.x * 16 + (size_t)half * 8;
  double s = 0.0, s2 = 0.0;
  for (int u = 0; u < 8; u++) {
    const size_t n = nb + u;
    double p = (double)P[n * 128 + ch];
    double mx = -1.0e300, mn = 1.0e300;
    for (int k = 0; k < KNN_K; k++) {
      int j = idx[n * KNN_K + k];
      double h = p + (double)Q[(size_t)j * 128 + ch];
      h = h > 0.0 ? h : 0.0;
      mx = h > mx ? h : mx;
      mn = h < mn ? h : mn;
      s += h; s2 += h * h;
    }
    hmax[n * 128 + ch] = (float)mx;
    hmin[n * 128 + ch] = (float)mn;
  }
  red0[t] = s; red1[t] = s2;
  __syncthreads();
  if (t < 128) {
    atomicAdd(&stats[ch],       red0[t] + red0[t + 128]);
    atomicAdd(&stats[128 + ch], red1[t] + red1[t + 128]);
  }
}

__global__ void zero_stats_d(double* __restrict__ stats) {
  stats[threadIdx.x] = 0.0;
}

__global__ void bn_finalize_d(const double* __restrict__ stats, const float* __restrict__ g,
                              const float* __restrict__ beta, double* __restrict__ ss) {
  int ch = threadIdx.x;
  const double inv = 1.0 / ((double)N_PTS * (double)KNN_K);
  double mu = stats[ch] * inv;
  double var = stats[128 + ch] * inv - mu * mu;
  double sc = (double)g[ch] / sqrt(var + 1e-5);
  ss[ch] = sc;
  ss[128 + ch] = (double)beta[ch] - mu * sc;
}

__global__ void ec_out_d(const float* __restrict__ hmax, const float* __restrict__ hmin,
                         const double* __restrict__ ss, float* __restrict__ h_f) {
  size_t i = (size_t)blockIdx.x * 256 + threadIdx.x;
  int ch = (int)(i & 127);
  double sc = ss[ch];
  double v = sc >= 0.0 ? (double)hmax[i] : (double)hmin[i];
  h_f[i] = (float)(v * sc + ss[128 + ch]);
}

// ---------------------------------------------------------------------------
__global__ void head1_kernel(const float* __restrict__ h2, const float* __restrict__ lw1,
                             const float* __restrict__ lb1, float* __restrict__ T) {
  int gid = blockIdx.x * 256 + threadIdx.x;
  int n = gid >> 6, hc = gid & 63;
  const float* hr = h2 + (size_t)n * 128;
  double a = (double)lb1[hc];
  for (int d = 0; d < 128; d++) {
    double v = (double)hr[d];
    v = v > 0.0 ? v : 0.0;
    a += v * (double)lw1[(size_t)d * 64 + hc];
  }
  T[gid] = (float)(a > 0.0 ? a : 0.0);
}

__global__ void head2_kernel(const float* __restrict__ T, const float* __restrict__ lw2,
                             const float* __restrict__ lb2, float* __restrict__ out) {
  int gid = blockIdx.x * 256 + threadIdx.x;
  int n = gid >> 6, oc = gid & 63;
  const float* tr = T + (size_t)n * 64;
  double a = (double)lb2[oc];
  for (int d = 0; d < 64; d++) a += (double)tr[d] * (double)lw2[(size_t)d * 64 + oc];
  out[gid] = (float)a;
}

// ---------------------------------------------------------------------------
extern "C" void kernel_launch(void* const* d_in, const int* in_sizes, int n_in,
                              void* d_out, int out_size, void* d_ws, size_t ws_size,
                              hipStream_t stream) {
  (void)in_sizes; (void)n_in; (void)out_size; (void)ws_size;
  const float* x     = (const float*)d_in[0];
  const float* W1    = (const float*)d_in[1];
  const float* b1    = (const float*)d_in[2];
  const float* g1    = (const float*)d_in[3];
  const float* beta1 = (const float*)d_in[4];
  const float* W2    = (const float*)d_in[5];
  const float* b2    = (const float*)d_in[6];
  const float* g2    = (const float*)d_in[7];
  const float* beta2 = (const float*)d_in[8];
  const float* lw1   = (const float*)d_in[9];
  const float* lb1   = (const float*)d_in[10];
  const float* lw2   = (const float*)d_in[11];
  const float* lb2   = (const float*)d_in[12];
  float* out = (float*)d_out;

  char* w = (char*)d_ws;
  size_t off = 0;
  auto alloc = [&](size_t bytes) { char* p = w + off; off += (bytes + 255) & ~(size_t)255; return p; };
  float*  sq    = (float*) alloc(N_PTS * 4);
  float*  tau   = (float*) alloc(N_PTS * 4);
  int*    cnt   = (int*)   alloc(N_PTS * 4);
  int*    list  = (int*)   alloc((size_t)N_PTS * CAP * 4);      // 28 MB
  int*    idx   = (int*)   alloc((size_t)N_PTS * KNN_K * 4);    //  2 MB
  unsigned short* xhi = (unsigned short*)alloc((size_t)N_PTS * HDIM * 2);
  unsigned short* xlo = (unsigned short*)alloc((size_t)N_PTS * HDIM * 2);
  float*  P     = (float*) alloc((size_t)N_PTS * HDIM * 4);
  float*  Q     = (float*) alloc((size_t)N_PTS * HDIM * 4);
  float*  hmax  = (float*) alloc((size_t)N_PTS * HDIM * 4);
  float*  hmin  = (float*) alloc((size_t)N_PTS * HDIM * 4);
  double* stats = (double*)alloc(2 * HDIM * 8);
  double* ss    = (double*)alloc(2 * HDIM * 8);
  float*  h1f   = (float*) alloc((size_t)N_PTS * HDIM * 4);
  float*  h2f   = P;        // reuse (P dead after gather2)
  float*  T     = Q;        // reuse (Q dead after gather2)

  // ---- stage 1: knn on x (C=64) ----
  sqnorm_np_kernel<64><<<N_PTS / 256, 256, 0, stream>>>(x, sq);
  split_bf16_kernel<<<N_PTS * 64 / 256, 256, 0, stream>>>(x, xhi, xlo, N_PTS * 64);
  knn_tau<64><<<N_PTS / 64, 512, 0, stream>>>(xhi, xlo, sq, 0.05f, tau);
  zero_cnt_kernel<<<N_PTS / 256, 256, 0, stream>>>(cnt);
  knn_filter<64><<<dim3(N_PTS / 64, 4), 512, 0, stream>>>(xhi, xlo, sq, tau, cnt, list);
  knn_refine_np<64><<<N_PTS, CAP, 0, stream>>>(x, sq, cnt, list, idx);

  // ---- edge conv 1 (fp64) ----
  pq_kernel<64><<<N_PTS * 128 / 256, 256, 0, stream>>>(x, W1, b1, P, Q);
  zero_stats_d<<<1, 256, 0, stream>>>(stats);
  edge_gather2<<<N_PTS / 16, 256, 0, stream>>>(P, Q, idx, hmax, hmin, stats);
  bn_finalize_d<<<1, 128, 0, stream>>>(stats, g1, beta1, ss);
  ec_out_d<<<N_PTS * HDIM / 256, 256, 0, stream>>>(hmax, hmin, ss, h1f);

  // ---- stage 2: knn on h1 (C=128) ----
  sqnorm_np_kernel<128><<<N_PTS / 256, 256, 0, stream>>>(h1f, sq);
  split_bf16_kernel<<<N_PTS * 128 / 256, 256, 0, stream>>>(h1f, xhi, xlo, N_PTS * 128);
  knn_tau<128><<<N_PTS / 64, 512, 0, stream>>>(xhi, xlo, sq, 0.2f, tau);
  zero_cnt_kernel<<<N_PTS / 256, 256, 0, stream>>>(cnt);
  knn_filter<128><<<dim3(N_PTS / 64, 4), 512, 0, stream>>>(xhi, xlo, sq, tau, cnt, list);
  knn_refine_np<128><<<N_PTS, CAP, 0, stream>>>(h1f, sq, cnt, list, idx);

  // ---- edge conv 2 (fp64) ----
  pq_kernel<128><<<N_PTS * 128 / 256, 256, 0, stream>>>(h1f, W2, b2, P, Q);
  zero_stats_d<<<1, 256, 0, stream>>>(stats);
  edge_gather2<<<N_PTS / 16, 256, 0, stream>>>(P, Q, idx, hmax, hmin, stats);
  bn_finalize_d<<<1, 128, 0, stream>>>(stats, g2, beta2, ss);
  ec_out_d<<<N_PTS * HDIM / 256, 256, 0, stream>>>(hmax, hmin, ss, h2f);

  // ---- head (fp64) ----
  head1_kernel<<<N_PTS * 64 / 256, 256, 0, stream>>>(h2f, lw1, lb1, T);
  head2_kernel<<<N_PTS * 64 / 256, 256, 0, stream>>>(T, lw2, lb2, out);
}

// Round 9
// 2083.698 us; speedup vs baseline: 8.4971x; 1.6721x over previous
//
#include <hip/hip_runtime.h>
#include <hip/hip_bf16.h>
#include <math.h>

#define N_PTS 16384
#define KNN_K 32
#define CAP 512            // per-query filtered candidate list capacity
#define HDIM 128
#define TSAMP 4096         // tau sample: first TSAMP rows (subset order-stat bound)
#define NSLICE 4

typedef __attribute__((ext_vector_type(8))) short bf16x8;
typedef __attribute__((ext_vector_type(8))) unsigned short us8;
typedef __attribute__((ext_vector_type(4))) float f32x4;

// ---------------------------------------------------------------------------
// numpy-pairwise fp32 sum of squares per row (np.sum(x*x, axis=1) replica).
template<int C>
__global__ void sqnorm_np_kernel(const float* __restrict__ feat, float* __restrict__ sq) {
  int r = blockIdx.x * 256 + threadIdx.x;
  if (r >= N_PTS) return;
  const float* xr = feat + (size_t)r * C;
  float acc[8];
  #pragma unroll
  for (int j = 0; j < 8; j++) acc[j] = __fmul_rn(xr[j], xr[j]);
  for (int i = 8; i < C; i += 8) {
    #pragma unroll
    for (int j = 0; j < 8; j++)
      acc[j] = __fadd_rn(acc[j], __fmul_rn(xr[i + j], xr[i + j]));
  }
  float s01 = __fadd_rn(acc[0], acc[1]);
  float s23 = __fadd_rn(acc[2], acc[3]);
  float s45 = __fadd_rn(acc[4], acc[5]);
  float s67 = __fadd_rn(acc[6], acc[7]);
  sq[r] = __fadd_rn(__fadd_rn(s01, s23), __fadd_rn(s45, s67));
}

// ---------------------------------------------------------------------------
// hi/lo bf16 split with XOR chunk swizzle baked into the global layout:
// 16-B chunk c of row n is stored at chunk' = c ^ (n & (CH-1)). Rows stay
// contiguous, so a 32-row tile is still one contiguous block (tile copy OK),
// and LDS fragment reads become 2-way bank-aliased (free).
template<int C>
__global__ void split_swz_kernel(const float* __restrict__ x, unsigned short* __restrict__ hi,
                                 unsigned short* __restrict__ lo) {
  constexpr int CH = C / 8;
  int gid = blockIdx.x * 256 + threadIdx.x;    // N*CH threads
  int n = gid / CH, c = gid & (CH - 1);
  if (n >= N_PTS) return;
  const float* src = x + (size_t)n * C + c * 8;
  unsigned short h8[8], l8[8];
  #pragma unroll
  for (int j = 0; j < 8; j++) {
    float v = src[j];
    __hip_bfloat16 h = __float2bfloat16(v);
    float hf = __bfloat162float(h);
    __hip_bfloat16 l = __float2bfloat16(v - hf);
    h8[j] = *(unsigned short*)&h;
    l8[j] = *(unsigned short*)&l;
  }
  size_t o = (size_t)n * C + (size_t)(((c ^ (n & (CH - 1)))) * 8);
  *(us8*)(hi + o) = *(const us8*)h8;
  *(us8*)(lo + o) = *(const us8*)l8;
}

// ---------------------------------------------------------------------------
// KNN pass A (tau, sampled): distances of 64 queries vs the FIRST TSAMP rows
// (any-subset 32nd order statistic >= global 32nd — guaranteed cover).
// LDS-staged B tiles (loaded once per block, shared by all 8 waves), split-
// bf16 3-MFMA per kc (identical arithmetic to the filter). Per-lane top-2 of
// its stream; tau = 33rd-smallest of the 64-value stream union + margin.
template<int C>
__launch_bounds__(512)
__global__ void knn_tau(const unsigned short* __restrict__ xhi,
                        const unsigned short* __restrict__ xlo,
                        const float* __restrict__ sq,
                        float margin, float* __restrict__ tau) {
  constexpr int CH = C / 8, KC = C / 32;
  constexpr int NB = 32 * C * 2;               // bytes per tile matrix (hi or lo)
  constexpr int SEGS = (2 * NB) / 16 / 512;    // 16-B chunks per thread (1 or 2)
  __shared__ unsigned char Bs[2 * NB];
  __shared__ float tred[64][65];
  const int t = threadIdx.x;
  const int qbase = blockIdx.x * 64;
  const int wv = t >> 6, lane = t & 63, qd = lane >> 4, l16 = lane & 15;
  const int mi = (wv & 3) * 16, ni = (wv >> 2) * 16;

  bf16x8 ah[KC], al[KC];
  {
    const int arow = qbase + mi + l16;
    const int akey = arow & (CH - 1);
    #pragma unroll
    for (int kc = 0; kc < KC; kc++) {
      size_t o = (size_t)arow * C + (size_t)(((kc * 4 + qd) ^ akey) * 8);
      ah[kc] = *(const bf16x8*)(xhi + o);
      al[kc] = *(const bf16x8*)(xlo + o);
    }
  }
  int qr[4];
  #pragma unroll
  for (int r = 0; r < 4; r++) qr[r] = qbase + mi + qd * 4 + r;
  float t0[4], t1[4];
  #pragma unroll
  for (int r = 0; r < 4; r++) { t0[r] = INFINITY; t1[r] = INFINITY; }

  const int brow = ni + l16;
  const int bkey = brow & (CH - 1);

  us8 regs[SEGS];
  #pragma unroll
  for (int s = 0; s < SEGS; s++) {             // prefetch tile 0
    int boff = (t + s * 512) * 16;
    int mtx = boff >= NB;
    int off = boff & (NB - 1);
    regs[s] = *(const us8*)((mtx ? xlo : xhi) + off / 2);
  }
  for (int ti = 0; ti < TSAMP / 32; ti++) {
    __syncthreads();                           // (a) prev tile's reads done
    #pragma unroll
    for (int s = 0; s < SEGS; s++) {
      int boff = (t + s * 512) * 16;
      int mtx = boff >= NB;
      int off = boff & (NB - 1);
      *(us8*)&Bs[mtx * NB + off] = regs[s];
    }
    __syncthreads();                           // (b) tile ready
    if (ti + 1 < TSAMP / 32) {                 // prefetch next (flies over MFMA)
      #pragma unroll
      for (int s = 0; s < SEGS; s++) {
        int boff = (t + s * 512) * 16;
        int mtx = boff >= NB;
        int off = boff & (NB - 1);
        regs[s] = *(const us8*)((mtx ? xlo : xhi) + (size_t)(ti + 1) * 32 * C + off / 2);
      }
    }
    f32x4 acc = {0.f, 0.f, 0.f, 0.f};
    #pragma unroll
    for (int kc = 0; kc < KC; kc++) {
      size_t bo = (size_t)brow * (2 * C) + (size_t)(((kc * 4 + qd) ^ bkey) * 16);
      bf16x8 bh = *(const bf16x8*)&Bs[bo];
      bf16x8 bl = *(const bf16x8*)&Bs[NB + bo];
      acc = __builtin_amdgcn_mfma_f32_16x16x32_bf16(ah[kc], bh, acc, 0, 0, 0);
      acc = __builtin_amdgcn_mfma_f32_16x16x32_bf16(ah[kc], bl, acc, 0, 0, 0);
      acc = __builtin_amdgcn_mfma_f32_16x16x32_bf16(al[kc], bh, acc, 0, 0, 0);
    }
    const int j = ti * 32 + ni + l16;
    const float sj = sq[j];
    #pragma unroll
    for (int r = 0; r < 4; r++) {
      float d = fmaf(-2.f, acc[r], sj);
      if (d < t1[r] && j != qr[r]) {           // self-excluded: bound stays valid
        bool lt = d < t0[r];
        t1[r] = lt ? t0[r] : d;
        t0[r] = lt ? d : t0[r];
      }
    }
  }
  const int strm = ni + l16;
  #pragma unroll
  for (int r = 0; r < 4; r++) {
    tred[mi + qd * 4 + r][strm]      = t0[r];
    tred[mi + qd * 4 + r][32 + strm] = t1[r];
  }
  __syncthreads();
  const int tq = t >> 3, i0 = (t & 7) * 8;
  #pragma unroll
  for (int ii = 0; ii < 8; ii++) {
    const int i = i0 + ii;
    const float vi = tred[tq][i];
    int rank = 0;
    for (int m = 0; m < 64; m++) {
      float vm = tred[tq][m];
      rank += (vm < vi || (vm == vi && m < i)) ? 1 : 0;
    }
    if (rank == 32) tau[qbase + tq] = vi + margin;   // exactly one writer
  }
}

// ---------------------------------------------------------------------------
// KNN pass B (filter): identical split-bf16 MFMA distance, LDS-staged B tiles
// shared by the block's 8 waves; keep j if d <= tau[q]. Grid (qtile, jslice).
template<int C>
__launch_bounds__(512)
__global__ void knn_filter(const unsigned short* __restrict__ xhi,
                           const unsigned short* __restrict__ xlo,
                           const float* __restrict__ sq,
                           const float* __restrict__ tau,
                           int* __restrict__ cnt, int* __restrict__ list) {
  constexpr int CH = C / 8, KC = C / 32;
  constexpr int NB = 32 * C * 2;
  constexpr int SEGS = (2 * NB) / 16 / 512;
  constexpr int JSPAN = N_PTS / NSLICE;
  __shared__ unsigned char Bs[2 * NB];
  const int t = threadIdx.x;
  const int qbase = blockIdx.x * 64;
  const int jbase = blockIdx.y * JSPAN;
  const int wv = t >> 6, lane = t & 63, qd = lane >> 4, l16 = lane & 15;
  const int mi = (wv & 3) * 16, ni = (wv >> 2) * 16;

  bf16x8 ah[KC], al[KC];
  {
    const int arow = qbase + mi + l16;
    const int akey = arow & (CH - 1);
    #pragma unroll
    for (int kc = 0; kc < KC; kc++) {
      size_t o = (size_t)arow * C + (size_t)(((kc * 4 + qd) ^ akey) * 8);
      ah[kc] = *(const bf16x8*)(xhi + o);
      al[kc] = *(const bf16x8*)(xlo + o);
    }
  }
  int qr[4]; float tq[4];
  #pragma unroll
  for (int r = 0; r < 4; r++) {
    qr[r] = qbase + mi + qd * 4 + r;
    tq[r] = tau[qr[r]];
  }
  const int brow = ni + l16;
  const int bkey = brow & (CH - 1);

  us8 regs[SEGS];
  #pragma unroll
  for (int s = 0; s < SEGS; s++) {
    int boff = (t + s * 512) * 16;
    int mtx = boff >= NB;
    int off = boff & (NB - 1);
    regs[s] = *(const us8*)((mtx ? xlo : xhi) + (size_t)jbase * C + off / 2);
  }
  for (int ti = 0; ti < JSPAN / 32; ti++) {
    __syncthreads();
    #pragma unroll
    for (int s = 0; s < SEGS; s++) {
      int boff = (t + s * 512) * 16;
      int mtx = boff >= NB;
      int off = boff & (NB - 1);
      *(us8*)&Bs[mtx * NB + off] = regs[s];
    }
    __syncthreads();
    if (ti + 1 < JSPAN / 32) {
      #pragma unroll
      for (int s = 0; s < SEGS; s++) {
        int boff = (t + s * 512) * 16;
        int mtx = boff >= NB;
        int off = boff & (NB - 1);
        regs[s] = *(const us8*)((mtx ? xlo : xhi) + (size_t)(jbase + (ti + 1) * 32) * C + off / 2);
      }
    }
    f32x4 acc = {0.f, 0.f, 0.f, 0.f};
    #pragma unroll
    for (int kc = 0; kc < KC; kc++) {
      size_t bo = (size_t)brow * (2 * C) + (size_t)(((kc * 4 + qd) ^ bkey) * 16);
      bf16x8 bh = *(const bf16x8*)&Bs[bo];
      bf16x8 bl = *(const bf16x8*)&Bs[NB + bo];
      acc = __builtin_amdgcn_mfma_f32_16x16x32_bf16(ah[kc], bh, acc, 0, 0, 0);
      acc = __builtin_amdgcn_mfma_f32_16x16x32_bf16(ah[kc], bl, acc, 0, 0, 0);
      acc = __builtin_amdgcn_mfma_f32_16x16x32_bf16(al[kc], bh, acc, 0, 0, 0);
    }
    const int j = jbase + ti * 32 + ni + l16;
    const float sj = sq[j];
    #pragma unroll
    for (int r = 0; r < 4; r++) {
      float d = fmaf(-2.f, acc[r], sj);
      if (d <= tq[r] && j != qr[r]) {
        int pos = atomicAdd(&cnt[qr[r]], 1);
        if (pos < CAP) list[(size_t)qr[r] * CAP + pos] = j;
      }
    }
  }
}

__global__ void zero_cnt_kernel(int* __restrict__ cnt) {
  cnt[blockIdx.x * 256 + threadIdx.x] = 0;
}

// ---------------------------------------------------------------------------
// KNN refine (np-fp32-exact, unchanged): one block/query, thread t scores
// candidate t; rank by (d, index) = top_k's stable order.
template<int C>
__global__ void knn_refine_np(const float* __restrict__ feat, const float* __restrict__ sq,
                              const int* __restrict__ cnt, const int* __restrict__ list,
                              int* __restrict__ idx_out) {
  __shared__ float ds[CAP];
  __shared__ int   js[CAP];
  __shared__ float xqs[C];
  const int q = blockIdx.x;
  const int t = threadIdx.x;  // CAP threads
  for (int v = t; v < C; v += CAP) xqs[v] = feat[(size_t)q * C + v];
  int cq = cnt[q]; if (cq > CAP) cq = CAP;
  __syncthreads();
  float d = INFINITY; int j = 0x7fffffff;
  if (t < cq) {
    j = list[(size_t)q * CAP + t];
    const float* xj = feat + (size_t)j * C;
    float g = 0.f;
    for (int c = 0; c < C; c++) g = fmaf(xqs[c], xj[c], g);
    d = __fsub_rn(__fadd_rn(sq[q], sq[j]), __fmul_rn(2.f, g));
    ds[t] = d; js[t] = j;
  }
  __syncthreads();
  if (t < cq) {
    int rank = 0;
    for (int m = 0; m < cq; m++) {
      float dm = ds[m]; int jm = js[m];
      if (dm < d || (dm == d && jm < j)) rank++;
    }
    if (rank < KNN_K) idx_out[(size_t)q * KNN_K + rank] = j;
  }
}

// ---------------------------------------------------------------------------
// P[n][ch] = b[ch] + x[n]@(Wtop - Wbot)[:,ch];  Q[n][ch] = x[n]@Wbot[:,ch].
template<int C>
__global__ void pq_kernel(const float* __restrict__ feat, const float* __restrict__ W,
                          const float* __restrict__ b, float* __restrict__ P,
                          float* __restrict__ Q) {
  int gid = blockIdx.x * 256 + threadIdx.x;   // N*128 threads
  int n = gid >> 7, ch = gid & 127;
  const float* xr = feat + (size_t)n * C;
  double p = (double)b[ch], q = 0.0;
  for (int d = 0; d < C; d++) {
    double xv = (double)xr[d];
    p += xv * (double)W[(size_t)d * HDIM + ch];
    q += xv * (double)W[(size_t)(C + d) * HDIM + ch];
  }
  P[gid] = (float)(p - q);
  Q[gid] = (float)q;
}

// ---------------------------------------------------------------------------
__global__ void edge_gather2(const float* __restrict__ P, const float* __restrict__ Q,
                             const int* __restrict__ idx, float* __restrict__ hmax,
                             float* __restrict__ hmin, double* __restrict__ stats) {
  __shared__ double red0[256];
  __shared__ double red1[256];
  const int t = threadIdx.x;
  const int ch = t & 127, half = t >> 7;
  const size_t nb = (size_t)blockIdx.x * 16 + (size_t)half * 8;
  double s = 0.0, s2 = 0.0;
  for (int u = 0; u < 8; u++) {
    const size_t n = nb + u;
    double p = (double)P[n * 128 + ch];
    double mx = -1.0e300, mn = 1.0e300;
    for (int k = 0; k < KNN_K; k++) {
      int j = idx[n * KNN_K + k];
      double h = p + (double)Q[(size_t)j * 128 + ch];
      h = h > 0.0 ? h : 0.0;
      mx = h > mx ? h : mx;
      mn = h < mn ? h : mn;
      s += h; s2 += h * h;
    }
    hmax[n * 128 + ch] = (float)mx;
    hmin[n * 128 + ch] = (float)mn;
  }
  red0[t] = s; red1[t] = s2;
  __syncthreads();
  if (t < 128) {
    atomicAdd(&stats[ch],       red0[t] + red0[t + 128]);
    atomicAdd(&stats[128 + ch], red1[t] + red1[t + 128]);
  }
}

__global__ void zero_stats_d(double* __restrict__ stats) {
  stats[threadIdx.x] = 0.0;
}

__global__ void bn_finalize_d(const double* __restrict__ stats, const float* __restrict__ g,
                              const float* __restrict__ beta, double* __restrict__ ss) {
  int ch = threadIdx.x;
  const double inv = 1.0 / ((double)N_PTS * (double)KNN_K);
  double mu = stats[ch] * inv;
  double var = stats[128 + ch] * inv - mu * mu;
  double sc = (double)g[ch] / sqrt(var + 1e-5);
  ss[ch] = sc;
  ss[128 + ch] = (double)beta[ch] - mu * sc;
}

__global__ void ec_out_d(const float* __restrict__ hmax, const float* __restrict__ hmin,
                         const double* __restrict__ ss, float* __restrict__ h_f) {
  size_t i = (size_t)blockIdx.x * 256 + threadIdx.x;
  int ch = (int)(i & 127);
  double sc = ss[ch];
  double v = sc >= 0.0 ? (double)hmax[i] : (double)hmin[i];
  h_f[i] = (float)(v * sc + ss[128 + ch]);
}

// ---------------------------------------------------------------------------
__global__ void head1_kernel(const float* __restrict__ h2, const float* __restrict__ lw1,
                             const float* __restrict__ lb1, float* __restrict__ T) {
  int gid = blockIdx.x * 256 + threadIdx.x;
  int n = gid >> 6, hc = gid & 63;
  const float* hr = h2 + (size_t)n * 128;
  double a = (double)lb1[hc];
  for (int d = 0; d < 128; d++) {
    double v = (double)hr[d];
    v = v > 0.0 ? v : 0.0;
    a += v * (double)lw1[(size_t)d * 64 + hc];
  }
  T[gid] = (float)(a > 0.0 ? a : 0.0);
}

__global__ void head2_kernel(const float* __restrict__ T, const float* __restrict__ lw2,
                             const float* __restrict__ lb2, float* __restrict__ out) {
  int gid = blockIdx.x * 256 + threadIdx.x;
  int n = gid >> 6, oc = gid & 63;
  const float* tr = T + (size_t)n * 64;
  double a = (double)lb2[oc];
  for (int d = 0; d < 64; d++) a += (double)tr[d] * (double)lw2[(size_t)d * 64 + oc];
  out[gid] = (float)a;
}

// ---------------------------------------------------------------------------
extern "C" void kernel_launch(void* const* d_in, const int* in_sizes, int n_in,
                              void* d_out, int out_size, void* d_ws, size_t ws_size,
                              hipStream_t stream) {
  (void)in_sizes; (void)n_in; (void)out_size; (void)ws_size;
  const float* x     = (const float*)d_in[0];
  const float* W1    = (const float*)d_in[1];
  const float* b1    = (const float*)d_in[2];
  const float* g1    = (const float*)d_in[3];
  const float* beta1 = (const float*)d_in[4];
  const float* W2    = (const float*)d_in[5];
  const float* b2    = (const float*)d_in[6];
  const float* g2    = (const float*)d_in[7];
  const float* beta2 = (const float*)d_in[8];
  const float* lw1   = (const float*)d_in[9];
  const float* lb1   = (const float*)d_in[10];
  const float* lw2   = (const float*)d_in[11];
  const float* lb2   = (const float*)d_in[12];
  float* out = (float*)d_out;

  char* w = (char*)d_ws;
  size_t off = 0;
  auto alloc = [&](size_t bytes) { char* p = w + off; off += (bytes + 255) & ~(size_t)255; return p; };
  float*  sq    = (float*) alloc(N_PTS * 4);
  float*  tau   = (float*) alloc(N_PTS * 4);
  int*    cnt   = (int*)   alloc(N_PTS * 4);
  int*    list  = (int*)   alloc((size_t)N_PTS * CAP * 4);      // 32 MB
  int*    idx   = (int*)   alloc((size_t)N_PTS * KNN_K * 4);    //  2 MB
  unsigned short* xhi = (unsigned short*)alloc((size_t)N_PTS * HDIM * 2);
  unsigned short* xlo = (unsigned short*)alloc((size_t)N_PTS * HDIM * 2);
  float*  P     = (float*) alloc((size_t)N_PTS * HDIM * 4);
  float*  Q     = (float*) alloc((size_t)N_PTS * HDIM * 4);
  float*  hmax  = (float*) alloc((size_t)N_PTS * HDIM * 4);
  float*  hmin  = (float*) alloc((size_t)N_PTS * HDIM * 4);
  double* stats = (double*)alloc(2 * HDIM * 8);
  double* ss    = (double*)alloc(2 * HDIM * 8);
  float*  h1f   = (float*) alloc((size_t)N_PTS * HDIM * 4);
  float*  h2f   = P;        // reuse (P dead after gather2)
  float*  T     = Q;        // reuse (Q dead after gather2)

  // ---- stage 1: knn on x (C=64) ----
  sqnorm_np_kernel<64><<<N_PTS / 256, 256, 0, stream>>>(x, sq);
  split_swz_kernel<64><<<N_PTS * 8 / 256, 256, 0, stream>>>(x, xhi, xlo);
  knn_tau<64><<<N_PTS / 64, 512, 0, stream>>>(xhi, xlo, sq, 0.05f, tau);
  zero_cnt_kernel<<<N_PTS / 256, 256, 0, stream>>>(cnt);
  knn_filter<64><<<dim3(N_PTS / 64, NSLICE), 512, 0, stream>>>(xhi, xlo, sq, tau, cnt, list);
  knn_refine_np<64><<<N_PTS, CAP, 0, stream>>>(x, sq, cnt, list, idx);

  // ---- edge conv 1 (fp64) ----
  pq_kernel<64><<<N_PTS * 128 / 256, 256, 0, stream>>>(x, W1, b1, P, Q);
  zero_stats_d<<<1, 256, 0, stream>>>(stats);
  edge_gather2<<<N_PTS / 16, 256, 0, stream>>>(P, Q, idx, hmax, hmin, stats);
  bn_finalize_d<<<1, 128, 0, stream>>>(stats, g1, beta1, ss);
  ec_out_d<<<N_PTS * HDIM / 256, 256, 0, stream>>>(hmax, hmin, ss, h1f);

  // ---- stage 2: knn on h1 (C=128) ----
  sqnorm_np_kernel<128><<<N_PTS / 256, 256, 0, stream>>>(h1f, sq);
  split_swz_kernel<128><<<N_PTS * 16 / 256, 256, 0, stream>>>(h1f, xhi, xlo);
  knn_tau<128><<<N_PTS / 64, 512, 0, stream>>>(xhi, xlo, sq, 0.2f, tau);
  zero_cnt_kernel<<<N_PTS / 256, 256, 0, stream>>>(cnt);
  knn_filter<128><<<dim3(N_PTS / 64, NSLICE), 512, 0, stream>>>(xhi, xlo, sq, tau, cnt, list);
  knn_refine_np<128><<<N_PTS, CAP, 0, stream>>>(h1f, sq, cnt, list, idx);

  // ---- edge conv 2 (fp64) ----
  pq_kernel<128><<<N_PTS * 128 / 256, 256, 0, stream>>>(h1f, W2, b2, P, Q);
  zero_stats_d<<<1, 256, 0, stream>>>(stats);
  edge_gather2<<<N_PTS / 16, 256, 0, stream>>>(P, Q, idx, hmax, hmin, stats);
  bn_finalize_d<<<1, 128, 0, stream>>>(stats, g2, beta2, ss);
  ec_out_d<<<N_PTS * HDIM / 256, 256, 0, stream>>>(hmax, hmin, ss, h2f);

  // ---- head (fp64) ----
  head1_kernel<<<N_PTS * 64 / 256, 256, 0, stream>>>(h2f, lw1, lb1, T);
  head2_kernel<<<N_PTS * 64 / 256, 256, 0, stream>>>(T, lw2, lb2, out);
}